// Round 9
// baseline (183.365 us; speedup 1.0000x reference)
//
#include <hip/hip_runtime.h>
#include <math.h>

// OrthoLayer (256->256): out = x @ M + bias, where M composes 509 brick-wall
// Givens steps. M is built once per call by running the scan on identity rows
// (256 register-resident waves, DPP neighbor exchange, 8-deep table prefetch),
// then applied as a single fp32 GEMM.
//
// Scratch lives in module-level __device__ arrays (allocated at .so load, no
// hipMalloc, no d_ws dependency -> no OOB risk if ws_size is small):
//   g_cs [528*128] float2  cos/sin per (step,pair); identity pad
//   g_cso[264*64]  float2  csO[u][l] = cs[2u+1][2l-1] (identity at l=0)
//   g_M  [256*256] float   row-major: out[i][c] = sum_k x[i][k]*M[k][c]

#define T_STEPS 509
#define T_PAD   528                          // covers prefetch to t = 2*263+1 = 527
#define PMAX    128
#define WDIM    256
#define NU2     256                          // padded (even,odd) iterations (t=0..511)
#define UPAD    264                          // csO entries (prefetch to u=263)
#define CS_ELEMS  (T_PAD * PMAX)             // 67584
#define CSO_ELEMS (UPAD * 64)                // 16896

__device__ __align__(16) float2 g_cs[CS_ELEMS];
__device__ __align__(16) float2 g_cso[CSO_ELEMS];
__device__ __align__(16) float  g_M[WDIM * WDIM];

// theta pairs consumed before step t (verified: off(0)=0, off(255)=16384, off(509)=32640)
__device__ __forceinline__ int theta_off(int t) {
    if (t <= 255) return t + ((t - 1) * (t - 1)) / 4;
    int U = t - 255;
    return 16384 + 127 * U - ((U - 1) * (U - 1)) / 4;
}
// valid rotation pairs at step t; <=0 for pad steps t>=509 (never indexes thetas)
__device__ __forceinline__ int npairs(int t) {
    return ((t < 255 ? t + 2 : 510 - t) - (t & 1)) >> 1;
}

// DPP wave shifts (gfx9-lineage controls, retained on CDNA): 0x138 wave_shr1
// (lane n <- lane n-1), 0x130 wave_shl1 (lane n <- lane n+1). Boundary lanes
// receive old=0 under either bound_ctrl semantic; every use multiplies them by
// a table-identity 0 coefficient, so they are value-safe.
__device__ __forceinline__ float dpp_shr1(float v) {  // == __shfl_up(v,1)
    return __int_as_float(__builtin_amdgcn_update_dpp(
        0, __float_as_int(v), 0x138, 0xF, 0xF, false));
}
__device__ __forceinline__ float dpp_shl1(float v) {  // == __shfl_down(v,1)
    return __int_as_float(__builtin_amdgcn_update_dpp(
        0, __float_as_int(v), 0x130, 0xF, 0xF, false));
}

// ---------------- tables: cs + csO in one launch (both direct from thetas) ---
__global__ __launch_bounds__(256) void build_tables(const float* __restrict__ thetas) {
    int idx = blockIdx.x * 256 + threadIdx.x;
    if (idx < CS_ELEMS) {
        int t = idx >> 7, pp = idx & 127;
        float c = 1.f, s = 0.f;
        if (pp < npairs(t)) sincosf(thetas[theta_off(t) + pp], &s, &c);
        g_cs[idx] = make_float2(c, s);
    } else if (idx < CS_ELEMS + CSO_ELEMS) {
        int j = idx - CS_ELEMS;
        int u = j >> 6, l = j & 63;
        int t = 2 * u + 1, pp = 2 * l - 1;       // pair left of lane l's column block
        float c = 1.f, s = 0.f;
        if (l > 0 && pp < npairs(t)) sincosf(thetas[theta_off(t) + pp], &s, &c);
        g_cso[j] = make_float2(c, s);
    }
}

// ---------------- build M: one wave per row, columns 4l..4l+3 in registers ---
// Even step 2u: pairs (4l,4l+1),(4l+2,4l+3) intra-lane via F=(c2l,s2l,c2l+1,s2l+1).
// Odd step 2u+1: (4l+1,4l+2) intra-lane (G.x,G.y); (4l-1,4l) via dpp_shr1(x3)+H;
// (4l+3,4l+4) via dpp_shl1(x0)+(G.z,G.w). Invalid pairs are identity in the
// tables, which also neutralizes DPP boundary values at lanes 0/63.
// Tables prefetched 8 iterations deep (~240 cy cover >= L2-hit latency); loop
// padded to 256 iterations with identity steps so unroll-8 slot indices stay
// compile-time constants (no scratch). 1 wave/CU, 256 blocks over 256 CUs:
// per-iter cost ~max(VALU issue ~45cy, L1 fill ~40cy) -> ~4-5us chain floor.
__global__ __launch_bounds__(64) void build_M() {
    const int r = blockIdx.x;           // 0..255
    const int l = threadIdx.x;          // 0..63
    const int c0 = 4 * l;
    float x0 = (c0 + 0 == r) ? 1.f : 0.f;
    float x1 = (c0 + 1 == r) ? 1.f : 0.f;
    float x2 = (c0 + 2 == r) ? 1.f : 0.f;
    float x3 = (c0 + 3 == r) ? 1.f : 0.f;
    const float4* p = reinterpret_cast<const float4*>(g_cs) + l;
    const float2* q = g_cso + l;        // q[u*64] = (c,s) of pair 2l-1 at step 2u+1

    float4 Fb[8], Gb[8];
    float2 Hb[8];
#pragma unroll
    for (int j = 0; j < 8; ++j) {
        Fb[j] = p[(2 * j) * 64];
        Gb[j] = p[(2 * j + 1) * 64];
        Hb[j] = q[j * 64];
    }
#pragma unroll 8
    for (int u = 0; u < NU2; ++u) {
        const int s = u & 7;            // static under unroll-8
        float4 F = Fb[s], G = Gb[s];
        float2 H = Hb[s];
        const int un = u + 8;           // max 263; tables padded through 527/263
        Fb[s] = p[(2 * un) * 64];
        Gb[s] = p[(2 * un + 1) * 64];
        Hb[s] = q[un * 64];
        float a, b;
        // even step 2u
        a = x0; b = x1; x0 = a * F.x - b * F.y; x1 = a * F.y + b * F.x;
        a = x2; b = x3; x2 = a * F.z - b * F.w; x3 = a * F.w + b * F.z;
        // odd step 2u+1 (capture post-even neighbor values via DPP)
        float aB = dpp_shr1(x3);        // col 4l-1 (lane l-1's x3)
        float bC = dpp_shl1(x0);        // col 4l+4 (lane l+1's x0)
        a = x1; b = x2; x1 = a * G.x - b * G.y; x2 = a * G.y + b * G.x;
        x0 = aB * H.y + x0 * H.x;       // pair (4l-1,4l): we own b
        x3 = x3 * G.z - bC * G.w;       // pair (4l+3,4l+4): we own a
    }
    reinterpret_cast<float4*>(g_M)[r * 64 + l] = make_float4(x0, x1, x2, x3);
}

// ---------------- out = x @ M + bias ----------------------------------------
// 64x64 tile, 512 threads (8 waves, 1 block/CU -> 2 waves/SIMD), per-thread
// 1 row x 8 cols (float4 pair c4, c4+8). Per wave per 4k-iter: ONE broadcast
// ds_read_b128 (8 rows x 8-lane broadcast; row-swizzle (r&7) spreads the 8
// addresses over all 32 banks, conflict-free) + 8 coalesced 128B M loads.
// Budgets per CU per 4k-iter: DS ~96cy, L1 ~128cy, VALU 128cy -> VALU/L1
// co-critical; unroll-4 k-loop gives MLP to hide first-touch L2 latency.
// Blocks XCD-grouped so a row-panel's 4 col-blocks share one per-XCD L2.
__global__ __launch_bounds__(512) void ortho_gemm(const float* __restrict__ X,
                                                  const float* __restrict__ bias,
                                                  float* __restrict__ out,
                                                  int nrb) {
    __shared__ float xs[64 * 256];      // 64 KB
    const int tid = threadIdx.x;
    const int id = blockIdx.x;
    int rowblk, colblk;
    if (nrb == 64) {                    // group a row-panel's 4 col-blocks per XCD
        const int xcd = id & 7, slot = id >> 3;
        rowblk = xcd * 8 + (slot >> 2);
        colblk = slot & 3;
    } else {
        rowblk = id >> 2;
        colblk = id & 3;
    }
    const int row0 = rowblk * 64;
    const int col0 = colblk * 64;

    // stage x: 64 rows x 64 float4 = 4096 float4, 8 per thread, coalesced.
    // Each staging wave handles one row (r = it*8 + w uniform, kq = lane).
#pragma unroll
    for (int it = 0; it < 8; ++it) {
        int idx = tid + it * 512;
        int r = idx >> 6;               // wave-uniform -> 1KB coalesced global read
        int kq = idx & 63;
        float4 v = reinterpret_cast<const float4*>(X)[(row0 + r) * 64 + kq];
        int ko = (kq * 4) ^ ((r & 7) << 2);   // swizzle k bits 2-4 by row bits 0-2
        *reinterpret_cast<float4*>(&xs[r * 256 + ko]) = v;
    }
    __syncthreads();

    const int tx = tid & 7;             // 8 col-quads; partner at +8 -> 64 cols
    const int ty = tid >> 3;            // 64 rows, one per thread
    const int swz = (ty & 7) << 2;      // matches write swizzle for row ty
    const float4* M4 = reinterpret_cast<const float4*>(g_M);
    const int c4 = (col0 >> 2) + tx;

    float acc[8];
#pragma unroll
    for (int j = 0; j < 8; ++j) acc[j] = 0.f;

#pragma unroll 4
    for (int k0 = 0; k0 < 256; k0 += 4) {
        const int kk = k0 ^ swz;
        float4 a = *reinterpret_cast<const float4*>(&xs[ty * 256 + kk]);
        float4 mA0 = M4[(k0 + 0) * 64 + c4], mB0 = M4[(k0 + 0) * 64 + c4 + 8];
        float4 mA1 = M4[(k0 + 1) * 64 + c4], mB1 = M4[(k0 + 1) * 64 + c4 + 8];
        float4 mA2 = M4[(k0 + 2) * 64 + c4], mB2 = M4[(k0 + 2) * 64 + c4 + 8];
        float4 mA3 = M4[(k0 + 3) * 64 + c4], mB3 = M4[(k0 + 3) * 64 + c4 + 8];
#define KSTEP(s, mA, mB)                                                      \
        acc[0] += (s) * mA.x; acc[1] += (s) * mA.y;                           \
        acc[2] += (s) * mA.z; acc[3] += (s) * mA.w;                           \
        acc[4] += (s) * mB.x; acc[5] += (s) * mB.y;                           \
        acc[6] += (s) * mB.z; acc[7] += (s) * mB.w;
        KSTEP(a.x, mA0, mB0) KSTEP(a.y, mA1, mB1)
        KSTEP(a.z, mA2, mB2) KSTEP(a.w, mA3, mB3)
#undef KSTEP
    }

    const float4* b4 = reinterpret_cast<const float4*>(bias);
    float4 bva = b4[c4], bvb = b4[c4 + 8];
    float4* out4 = reinterpret_cast<float4*>(out);
    float4 oa = make_float4(acc[0] + bva.x, acc[1] + bva.y,
                            acc[2] + bva.z, acc[3] + bva.w);
    float4 ob = make_float4(acc[4] + bvb.x, acc[5] + bvb.y,
                            acc[6] + bvb.z, acc[7] + bvb.w);
    out4[(row0 + ty) * 64 + c4]     = oa;
    out4[(row0 + ty) * 64 + c4 + 8] = ob;
}

extern "C" void kernel_launch(void* const* d_in, const int* in_sizes, int n_in,
                              void* d_out, int out_size, void* d_ws, size_t ws_size,
                              hipStream_t stream) {
    const float* x      = (const float*)d_in[0];   // (B, 256) f32
    const float* thetas = (const float*)d_in[1];   // (32640,) f32
    const float* bias   = (const float*)d_in[2];   // (256,)   f32
    float* out = (float*)d_out;
    (void)d_ws; (void)ws_size;                     // scratch in __device__ globals

    const int B = in_sizes[0] / WDIM;              // 4096
    const int nrb = B / 64;

    build_tables<<<(CS_ELEMS + CSO_ELEMS + 255) / 256, 256, 0, stream>>>(thetas);
    build_M<<<WDIM, 64, 0, stream>>>();
    ortho_gemm<<<nrb * 4, 512, 0, stream>>>(x, bias, out, nrb);
}

// Round 10
// 156.134 us; speedup vs baseline: 1.1744x; 1.1744x over previous
//
#include <hip/hip_runtime.h>
#include <math.h>

// OrthoLayer (256->256): out = x @ M + bias, where M composes 509 brick-wall
// Givens steps. M is built once per call by running the scan on identity rows
// (256 register-resident waves, DPP neighbor exchange, 8-deep NAMED-REGISTER
// table prefetch), then applied as a single fp32 GEMM.
//
// Scratch lives in module-level __device__ arrays (no d_ws dependency):
//   g_cs [528*128] float2  cos/sin per (step,pair); identity pad
//   g_cso[264*64]  float2  csO[u][l] = cs[2u+1][2l-1] (identity at l=0)
//   g_M  [256*256] float   row-major: out[i][c] = sum_k x[i][k]*M[k][c]
//
// R9 lesson (measured): array-based prefetch buffers indexed by (u&7) were
// demoted to scratch by SROA before unrolling (VGPR_Count=36, 877 cy/iter,
// VALUBusy 3%) -> build_M ran 93.6us. Fix: named registers + macro-expanded
// 8-step body so every access is compile-time static (rule #20).

#define T_STEPS 509
#define T_PAD   528                          // covers prefetch to t = 527
#define PMAX    128
#define WDIM    256
#define CS_ELEMS  (T_PAD * PMAX)             // 67584 float2 = 33792 float4
#define CSO_ELEMS (264 * 64)                 // 16896 float2 (prefetch to u=263)

__device__ __align__(16) float2 g_cs[CS_ELEMS];
__device__ __align__(16) float2 g_cso[CSO_ELEMS];
__device__ __align__(16) float  g_M[WDIM * WDIM];

// theta pairs consumed before step t (verified: off(0)=0, off(255)=16384, off(509)=32640)
__device__ __forceinline__ int theta_off(int t) {
    if (t <= 255) return t + ((t - 1) * (t - 1)) / 4;
    int U = t - 255;
    return 16384 + 127 * U - ((U - 1) * (U - 1)) / 4;
}
// valid rotation pairs at step t; <=0 for pad steps t>=509 (never indexes thetas)
__device__ __forceinline__ int npairs(int t) {
    return ((t < 255 ? t + 2 : 510 - t) - (t & 1)) >> 1;
}

// DPP wave shifts: 0x138 wave_shr1 (lane n <- n-1), 0x130 wave_shl1 (lane n <- n+1).
// Boundary lanes receive old=0; every use multiplies them by a table-identity 0.
__device__ __forceinline__ float dpp_shr1(float v) {
    return __int_as_float(__builtin_amdgcn_update_dpp(
        0, __float_as_int(v), 0x138, 0xF, 0xF, false));
}
__device__ __forceinline__ float dpp_shl1(float v) {
    return __int_as_float(__builtin_amdgcn_update_dpp(
        0, __float_as_int(v), 0x130, 0xF, 0xF, false));
}

// ---------------- tables: cs + csO in one launch (both direct from thetas) ---
__global__ __launch_bounds__(256) void build_tables(const float* __restrict__ thetas) {
    int idx = blockIdx.x * 256 + threadIdx.x;   // grid covers exactly 84480
    if (idx < CS_ELEMS) {
        int t = idx >> 7, pp = idx & 127;
        float c = 1.f, s = 0.f;
        if (pp < npairs(t)) sincosf(thetas[theta_off(t) + pp], &s, &c);
        g_cs[idx] = make_float2(c, s);
    } else {
        int j = idx - CS_ELEMS;
        int u = j >> 6, l = j & 63;
        int t = 2 * u + 1, pp = 2 * l - 1;       // pair left of lane l's column block
        float c = 1.f, s = 0.f;
        if (l > 0 && pp < npairs(t)) sincosf(thetas[theta_off(t) + pp], &s, &c);
        g_cso[j] = make_float2(c, s);
    }
}

// ---------------- build M: one wave per row, columns 4l..4l+3 in registers ---
// Even step 2u: pairs (4l,4l+1),(4l+2,4l+3) intra-lane via F=(c2l,s2l,c2l+1,s2l+1).
// Odd step 2u+1: (4l+1,4l+2) intra-lane (G.x,G.y); (4l-1,4l) via dpp_shr1(x3)+H;
// (4l+3,4l+4) via dpp_shl1(x0)+(G.z,G.w). Invalid pairs are identity in the
// tables, which also neutralizes DPP boundary values at lanes 0/63.
// 8-slot software pipeline in NAMED registers (~80 VGPR of coefficient state);
// loads for u+8 issue in slot u's body -> ~400cy cover >= L2-hit latency.
// 256 padded iterations (u=0..255; t=509..511 identity), 32 macro-iters x 8.
__global__ __launch_bounds__(64) void build_M() {
    const int r = blockIdx.x;           // 0..255
    const int l = threadIdx.x;          // 0..63
    const int c0 = 4 * l;
    float x0 = (c0 + 0 == r) ? 1.f : 0.f;
    float x1 = (c0 + 1 == r) ? 1.f : 0.f;
    float x2 = (c0 + 2 == r) ? 1.f : 0.f;
    float x3 = (c0 + 3 == r) ? 1.f : 0.f;
    const float4* p = reinterpret_cast<const float4*>(g_cs) + l;  // p[t*64] at step t
    const float2* q = g_cso + l;                                  // q[u*64] at step 2u+1

    float4 F0, F1, F2, F3, F4, F5, F6, F7;
    float4 G0, G1, G2, G3, G4, G5, G6, G7;
    float2 H0, H1, H2, H3, H4, H5, H6, H7;
#define LOAD8(j) do {                                                         \
        F##j = p[(2 * (j)) * 64];                                             \
        G##j = p[(2 * (j) + 1) * 64];                                         \
        H##j = q[(j) * 64];                                                   \
    } while (0)
    LOAD8(0); LOAD8(1); LOAD8(2); LOAD8(3);
    LOAD8(4); LOAD8(5); LOAD8(6); LOAD8(7);
#undef LOAD8

    for (int m = 0; m < 32; ++m) {
        // base pointers for the loads of u = 8(m+1)+j  (always in-bounds:
        // max float4 idx 33791 = CS_ELEMS/2-1; max float2 idx 16895)
        const float4* pn = p + 1024 * (m + 1);
        const float2* qn = q + 512 * (m + 1);
#define STEP(j) do {                                                          \
        float4 F = F##j; float4 G = G##j; float2 H = H##j;                    \
        F##j = pn[128 * (j)];                                                 \
        G##j = pn[128 * (j) + 64];                                            \
        H##j = qn[64 * (j)];                                                  \
        float a, b;                                                           \
        a = x0; b = x1; x0 = a * F.x - b * F.y; x1 = a * F.y + b * F.x;       \
        a = x2; b = x3; x2 = a * F.z - b * F.w; x3 = a * F.w + b * F.z;       \
        float aB = dpp_shr1(x3);                                              \
        float bC = dpp_shl1(x0);                                              \
        a = x1; b = x2; x1 = a * G.x - b * G.y; x2 = a * G.y + b * G.x;       \
        x0 = aB * H.y + x0 * H.x;                                             \
        x3 = x3 * G.z - bC * G.w;                                             \
    } while (0)
        STEP(0); STEP(1); STEP(2); STEP(3);
        STEP(4); STEP(5); STEP(6); STEP(7);
#undef STEP
    }
    reinterpret_cast<float4*>(g_M)[r * 64 + l] = make_float4(x0, x1, x2, x3);
}

// ---------------- out = x @ M + bias ----------------------------------------
// 64x64 tile, 512 threads (8 waves, 1 block/CU -> 2 waves/SIMD), per-thread
// 1 row x 8 cols (float4 pair c4, c4+8). Per wave per 4k-iter: ONE broadcast
// ds_read_b128 (8 rows x 8-lane broadcast; row-swizzle (r&7) spreads the 8
// addresses over all 32 banks, conflict-free) + 8 coalesced 128B M loads.
// Budgets per CU per 4k-iter: DS ~96cy, L1 ~128cy, VALU 128cy -> VALU/L1
// co-critical; unroll-4 k-loop gives MLP to hide first-touch L2 latency.
// Blocks XCD-grouped so a row-panel's 4 col-blocks share one per-XCD L2.
__global__ __launch_bounds__(512) void ortho_gemm(const float* __restrict__ X,
                                                  const float* __restrict__ bias,
                                                  float* __restrict__ out,
                                                  int nrb) {
    __shared__ float xs[64 * 256];      // 64 KB
    const int tid = threadIdx.x;
    const int id = blockIdx.x;
    int rowblk, colblk;
    if (nrb == 64) {                    // group a row-panel's 4 col-blocks per XCD
        const int xcd = id & 7, slot = id >> 3;
        rowblk = xcd * 8 + (slot >> 2);
        colblk = slot & 3;
    } else {
        rowblk = id >> 2;
        colblk = id & 3;
    }
    const int row0 = rowblk * 64;
    const int col0 = colblk * 64;

    // stage x: 64 rows x 64 float4 = 4096 float4, 8 per thread, coalesced.
#pragma unroll
    for (int it = 0; it < 8; ++it) {
        int idx = tid + it * 512;
        int r = idx >> 6;               // wave-uniform -> 1KB coalesced global read
        int kq = idx & 63;
        float4 v = reinterpret_cast<const float4*>(X)[(row0 + r) * 64 + kq];
        int ko = (kq * 4) ^ ((r & 7) << 2);   // swizzle k bits 2-4 by row bits 0-2
        *reinterpret_cast<float4*>(&xs[r * 256 + ko]) = v;
    }
    __syncthreads();

    const int tx = tid & 7;             // 8 col-quads; partner at +8 -> 64 cols
    const int ty = tid >> 3;            // 64 rows, one per thread
    const int swz = (ty & 7) << 2;      // matches write swizzle for row ty
    const float4* M4 = reinterpret_cast<const float4*>(g_M);
    const int c4 = (col0 >> 2) + tx;

    float acc[8];
#pragma unroll
    for (int j = 0; j < 8; ++j) acc[j] = 0.f;

#pragma unroll 4
    for (int k0 = 0; k0 < 256; k0 += 4) {
        const int kk = k0 ^ swz;
        float4 a = *reinterpret_cast<const float4*>(&xs[ty * 256 + kk]);
        float4 mA0 = M4[(k0 + 0) * 64 + c4], mB0 = M4[(k0 + 0) * 64 + c4 + 8];
        float4 mA1 = M4[(k0 + 1) * 64 + c4], mB1 = M4[(k0 + 1) * 64 + c4 + 8];
        float4 mA2 = M4[(k0 + 2) * 64 + c4], mB2 = M4[(k0 + 2) * 64 + c4 + 8];
        float4 mA3 = M4[(k0 + 3) * 64 + c4], mB3 = M4[(k0 + 3) * 64 + c4 + 8];
#define KSTEP(s, mA, mB)                                                      \
        acc[0] += (s) * mA.x; acc[1] += (s) * mA.y;                           \
        acc[2] += (s) * mA.z; acc[3] += (s) * mA.w;                           \
        acc[4] += (s) * mB.x; acc[5] += (s) * mB.y;                           \
        acc[6] += (s) * mB.z; acc[7] += (s) * mB.w;
        KSTEP(a.x, mA0, mB0) KSTEP(a.y, mA1, mB1)
        KSTEP(a.z, mA2, mB2) KSTEP(a.w, mA3, mB3)
#undef KSTEP
    }

    const float4* b4 = reinterpret_cast<const float4*>(bias);
    float4 bva = b4[c4], bvb = b4[c4 + 8];
    float4* out4 = reinterpret_cast<float4*>(out);
    float4 oa = make_float4(acc[0] + bva.x, acc[1] + bva.y,
                            acc[2] + bva.z, acc[3] + bva.w);
    float4 ob = make_float4(acc[4] + bvb.x, acc[5] + bvb.y,
                            acc[6] + bvb.z, acc[7] + bvb.w);
    out4[(row0 + ty) * 64 + c4]     = oa;
    out4[(row0 + ty) * 64 + c4 + 8] = ob;
}

extern "C" void kernel_launch(void* const* d_in, const int* in_sizes, int n_in,
                              void* d_out, int out_size, void* d_ws, size_t ws_size,
                              hipStream_t stream) {
    const float* x      = (const float*)d_in[0];   // (B, 256) f32
    const float* thetas = (const float*)d_in[1];   // (32640,) f32
    const float* bias   = (const float*)d_in[2];   // (256,)   f32
    float* out = (float*)d_out;
    (void)d_ws; (void)ws_size;                     // scratch in __device__ globals

    const int B = in_sizes[0] / WDIM;              // 4096
    const int nrb = B / 64;

    build_tables<<<(CS_ELEMS + CSO_ELEMS) / 256, 256, 0, stream>>>(thetas);
    build_M<<<WDIM, 64, 0, stream>>>();
    ortho_gemm<<<nrb * 4, 512, 0, stream>>>(x, bias, out, nrb);
}